// Round 13
// baseline (447.998 us; speedup 1.0000x reference)
//
#include <hip/hip_runtime.h>
#include <math.h>

#define CIN 64
#define NLAYERS 4
#define HOP 256
#define ILEN 4096
#define OLEN 32768
#define LROWS 24576   // rows of kk per layer = 64*128*3

typedef unsigned int uint;
typedef unsigned short ushort;
typedef __attribute__((ext_vector_type(8))) short bh8;
typedef __attribute__((ext_vector_type(4))) float f4;
typedef __attribute__((ext_vector_type(8))) unsigned short us8;
typedef __attribute__((ext_vector_type(4))) unsigned short us4;

__device__ __forceinline__ float lrelu(float x, float s) { return x >= 0.f ? x : s * x; }

__device__ __forceinline__ ushort f2b(float f) {       // fp32 -> bf16 (RNE)
  uint u = __float_as_uint(f);
  u = u + 0x7fff + ((u >> 16) & 1);
  return (ushort)(u >> 16);
}
__device__ __forceinline__ float b2f(ushort u) {
  return __uint_as_float(((uint)u) << 16);
}
__device__ __forceinline__ f4 mfma16(bh8 a, bh8 b, f4 c) {
  return __builtin_amdgcn_mfma_f32_16x16x32_bf16(a, b, c, 0, 0, 0);
}

// LDS-only barrier: drains DS ops (lgkmcnt) but lets global loads/stores stay in flight.
__device__ __forceinline__ void barrier_lgkm() {
  asm volatile("s_waitcnt lgkmcnt(0)" ::: "memory");
  __builtin_amdgcn_s_barrier();
  __builtin_amdgcn_sched_barrier(0);
}

// ---------------- mega prep: all weight transposes + xT, one launch ------------
// blocks [0,288): Ah/Ar/wct_b; [288,672): A3; [672,680): retired; [680,936): xT
__global__ void mega_prep(const float* __restrict__ kin_w, const float* __restrict__ kres_w,
                          const float* __restrict__ conv_w, const float* __restrict__ up_w,
                          const float* __restrict__ x,
                          ushort* __restrict__ Ah, ushort* __restrict__ Ar,
                          ushort* __restrict__ wct_b, ushort* __restrict__ A3,
                          ushort* __restrict__ xT) {
  __shared__ float ls[64][65];
  int bid = blockIdx.x, tid = threadIdx.x;
  if (bid < 288) {
    int i = bid * 256 + tid;
    if (i < 64 * 480) {
      int ch = i / 480, k = i % 480, tap = k / 96, cc = k % 96;
      float v = (cc < 80) ? kin_w[(ch * 80 + cc) * 5 + tap] : 0.f;
      Ah[i] = f2b(v);
    }
    if (i < 6 * 64 * 192) {
      int j = i / 12288, r = i % 12288, ch = r / 192, k = r % 192, tap = k >> 6, ci = k & 63;
      Ar[i] = f2b(kres_w[((j * 64 + ch) * 64 + ci) * 3 + tap]);
    }
    if (i < 4 * 3 * 64 * 64) {         // wct_b[l][ks][co][ci]
      int ci = i & 63, r = i >> 6, co = r & 63; r >>= 6; int ks = r % 3, l = r / 3;
      wct_b[i] = f2b(conv_w[((l * 64 + co) * 64 + ci) * 3 + ks]);
    }
  } else if (bid < 672) {
    int i = (bid - 288) * 256 + tid;   // A3[m=co*8+ph][k=(u+1)*64+ci]
    if (i < 512 * 192) {
      int k = i % 192, m = i / 192;
      int co = m >> 3, ph = m & 7;
      int u = k / 64 - 1, ci = k % 64;
      int kk0 = (11 - ph) & 7;
      int off = (ph < 4) ? -1 : 0;
      int tap = u - off;
      float v = 0.f;
      if (tap == 0 || tap == 1) {
        int a = 15 - kk0 - 8 * tap;
        v = up_w[(ci * 64 + co) * 16 + a];
      }
      A3[i] = f2b(v);
    }
  } else if (bid < 680) {
    // retired
  } else {
    int blk = bid - 680, b = blk >> 6, st = blk & 63;   // xT
    int s0 = st * 64;
    int c2 = tid >> 6, s = tid & 63;
    #pragma unroll
    for (int r = 0; r < 16; r++) {
      int ci = r * 4 + c2;
      ls[ci][s] = lrelu(x[((size_t)b * 64 + ci) * ILEN + s0 + s], 0.2f);
    }
    __syncthreads();
    int ci = tid & 63, r2 = tid >> 6;
    #pragma unroll
    for (int r = 0; r < 16; r++) {
      int ss = r * 4 + r2;
      xT[((size_t)b * 4098 + 1 + s0 + ss) * 64 + ci] = f2b(ls[ci][ss]);
    }
    if (st == 0) {
      if (tid < 64) xT[((size_t)b * 4098) * 64 + tid] = 0;
      else if (tid < 128) xT[((size_t)b * 4098 + 4097) * 64 + (tid - 64)] = 0;
    }
  }
}

// ---------------- fused kernel predictor, all-MFMA (unchanged) ----------------
__launch_bounds__(512)
__global__ void kp_fused(const float* __restrict__ c, const ushort* __restrict__ Ah,
                         const float* __restrict__ kin_b, const ushort* __restrict__ Ar,
                         const float* __restrict__ kres_b,
                         float* __restrict__ hsum, ushort* __restrict__ Bim) {
  __shared__ ushort cT[36 * 128];
  __shared__ ushort hT[34 * 64];
  __shared__ ushort aA[34 * 64];
  __shared__ ushort aB[34 * 64];
  int chunk = blockIdx.x, b = blockIdx.y;
  int l0 = chunk * 8;
  int tid = threadIdx.x;
  us8 z = {0, 0, 0, 0, 0, 0, 0, 0};
  for (int g = tid; g < 576; g += 512) *(us8*)(&cT[g * 8]) = z;
  for (int g = tid; g < 272; g += 512) {
    *(us8*)(&hT[g * 8]) = z; *(us8*)(&aA[g * 8]) = z; *(us8*)(&aB[g * 8]) = z;
  }
  __syncthreads();
  for (int g = tid; g < 2880; g += 512) {
    int cc = g / 36, r = g % 36;
    int gl = l0 - 10 + r;
    float v = (gl >= 0 && gl < 128) ? c[(b * 80 + cc) * 128 + gl] : 0.f;
    cT[(r * 16 + ((cc >> 3) ^ (r & 7))) * 8 + (cc & 7)] = f2b(v);
  }
  __syncthreads();
  int w = tid >> 6, lane = tid & 63, q = lane >> 4, ln = lane & 15;
  int mt = w >> 1, nt = w & 1;
  int n = nt * 16 + ln;
  int m0 = mt * 16;
  int gl = l0 - 8 + n;
  bool valid = (gl >= 0 && gl < 128);
  {
    f4 acc = {0.f, 0.f, 0.f, 0.f};
    #pragma unroll
    for (int s = 0; s < 15; s++) {
      int tap = s / 3;
      int chn = (s % 3) * 4 + q;
      bh8 a = *(const bh8*)(Ah + (m0 + ln) * 480 + s * 32 + q * 8);
      int row = n + tap;
      bh8 bf = *(const bh8*)(&cT[(row * 16 + (chn ^ (row & 7))) * 8]);
      acc = mfma16(a, bf, acc);
    }
    us4 o;
    #pragma unroll
    for (int r = 0; r < 4; r++) {
      float v = lrelu(acc[r] + kin_b[m0 + q * 4 + r], 0.1f);
      o[r] = valid ? f2b(v) : (ushort)0;
    }
    int row = n + 1, ch0 = m0 + q * 4;
    int off = (row * 8 + ((ch0 >> 3) ^ (row & 7))) * 8 + (ch0 & 7);
    *(us4*)(&hT[off]) = o;
    *(us4*)(&aA[off]) = o;
  }
  __syncthreads();
  for (int j = 0; j < 6; j++) {
    const ushort* ain = (j & 1) ? aB : aA;
    ushort* aout_ = (j & 1) ? aA : aB;
    f4 acc = {0.f, 0.f, 0.f, 0.f};
    #pragma unroll
    for (int s = 0; s < 6; s++) {
      int tap = s >> 1;
      int chn = (s & 1) * 4 + q;
      bh8 a = *(const bh8*)(Ar + j * 12288 + (m0 + ln) * 192 + s * 32 + q * 8);
      int row = n + tap;
      bh8 bf = *(const bh8*)(&ain[(row * 8 + (chn ^ (row & 7))) * 8]);
      acc = mfma16(a, bf, acc);
    }
    us4 o;
    #pragma unroll
    for (int r = 0; r < 4; r++) {
      float v = lrelu(acc[r] + kres_b[j * 64 + m0 + q * 4 + r], 0.1f);
      o[r] = valid ? f2b(v) : (ushort)0;
    }
    int row = n + 1, ch0 = m0 + q * 4;
    *(us4*)(&aout_[(row * 8 + ((ch0 >> 3) ^ (row & 7))) * 8 + (ch0 & 7)]) = o;
    __syncthreads();
  }
  int tch = tid >> 3, tcl = tid & 7;
  {
    int row = 9 + tcl;
    int off = (row * 8 + ((tch >> 3) ^ (row & 7))) * 8 + (tch & 7);
    hsum[(b * 64 + tch) * 128 + l0 + tcl] = b2f(hT[off]) + b2f(aA[off]);
  }
  {
    ushort* bp = Bim + ((size_t)(b * 128 + l0 + tcl)) * 192 + tch * 3;
    #pragma unroll
    for (int t = 0; t < 3; t++) {
      int row = 8 + tcl + t;
      int off = (row * 8 + ((tch >> 3) ^ (row & 7))) * 8 + (tch & 7);
      bp[t] = f2b(b2f(hT[off]) + b2f(aA[off]));
    }
  }
}

#define KKP 104

// ---------------- bias predictor as MFMA GEMM, widened grid: 64 blocks ----------------
__launch_bounds__(256)
__global__ void kb_mfma(const float* __restrict__ kb_w, const float* __restrict__ kb_b,
                        const ushort* __restrict__ Bim, float* __restrict__ bias_all) {
  __shared__ ushort As[128 * KKP];
  __shared__ ushort Bs[32 * KKP];
  __shared__ float bias_s[128];
  int n0 = blockIdx.x * 32;
  int m0 = blockIdx.y * 128;
  int tid = threadIdx.x;
  if (tid < 128) bias_s[tid] = kb_b[m0 + tid];
  const ushort* Bp = Bim + (size_t)n0 * 192;
  int w = tid >> 6, lane = tid & 63, q = lane >> 4, ln = lane & 15;
  int wm = (w >> 1) * 64, wn = (w & 1) * 16;
  f4 acc[4] = {};
  for (int kc = 0; kc < 2; kc++) {
    int kbase = kc * 96;
    __syncthreads();
    for (int i = tid; i < 128 * 24; i += 256) {
      int ml = i / 24, c4 = (i % 24) * 4;
      float4 v = *(const float4*)(kb_w + (size_t)(m0 + ml) * 192 + kbase + c4);
      us4 o = {f2b(v.x), f2b(v.y), f2b(v.z), f2b(v.w)};
      *(us4*)(&As[ml * KKP + c4]) = o;
    }
    for (int i = tid; i < 32 * 12; i += 256) {
      int n = i / 12, c8 = (i % 12) * 8;
      us8 v = *(const us8*)(Bp + (size_t)n * 192 + kbase + c8);
      *(us8*)(&Bs[n * KKP + c8]) = v;
    }
    __syncthreads();
    #pragma unroll
    for (int ks = 0; ks < 3; ks++) {
      int kb = ks * 32 + q * 8;
      bh8 bf = *(const bh8*)(&Bs[(wn + ln) * KKP + kb]);
      #pragma unroll
      for (int mi = 0; mi < 4; mi++) {
        bh8 af = *(const bh8*)(&As[(wm + mi * 16 + ln) * KKP + kb]);
        acc[mi] = mfma16(af, bf, acc[mi]);
      }
    }
  }
  int col = n0 + wn + ln;
  int b = col >> 7, l = col & 127;
  #pragma unroll
  for (int mi = 0; mi < 4; mi++) {
    #pragma unroll
    for (int r = 0; r < 4; r++) {
      int rloc = wm + mi * 16 + q * 4 + r;
      bias_all[((size_t)(b * 512 + m0 + rloc)) * 128 + l] = acc[mi][r] + bias_s[rloc];
    }
  }
}

// ---------------- upsample as MFMA GEMM (unchanged) ----------------
#define UP_KP 200
__launch_bounds__(256, 2)
__global__ void upsample_mfma(const ushort* __restrict__ xT, const ushort* __restrict__ A3,
                              const float* __restrict__ up_b, float* __restrict__ h) {
  __shared__ ushort As[128 * UP_KP];
  __shared__ ushort Bs[32 * UP_KP];
  int s0 = blockIdx.x * 32;
  int m0 = blockIdx.y * 128;
  int b  = blockIdx.z;
  int tid = threadIdx.x;
  {
    const ushort* src = A3 + (size_t)m0 * 192;
    for (int i = tid; i < 128 * 24; i += 256) {
      int m = i / 24, c8 = (i % 24) * 8;
      us8 v = *(const us8*)(src + (size_t)m * 192 + c8);
      *(us8*)(&As[m * UP_KP + c8]) = v;
    }
  }
  for (int i = tid; i < 32 * 24; i += 256) {
    int n = i / 24, rr = i % 24, u = rr / 8, c8 = (rr % 8) * 8;
    us8 v = *(const us8*)(xT + ((size_t)b * 4098 + s0 + n + u) * 64 + c8);
    *(us8*)(&Bs[n * UP_KP + u * 64 + c8]) = v;
  }
  __syncthreads();
  int w = tid >> 6, lane = tid & 63, q = lane >> 4, ln = lane & 15;
  int wm = w * 32;
  f4 acc[2][2] = {};
  #pragma unroll
  for (int ks = 0; ks < 6; ks++) {
    int kb = ks * 32 + q * 8;
    bh8 a0 = *(const bh8*)(&As[(wm + ln) * UP_KP + kb]);
    bh8 a1 = *(const bh8*)(&As[(wm + 16 + ln) * UP_KP + kb]);
    bh8 b0 = *(const bh8*)(&Bs[ln * UP_KP + kb]);
    bh8 b1 = *(const bh8*)(&Bs[(16 + ln) * UP_KP + kb]);
    acc[0][0] = mfma16(a0, b0, acc[0][0]);
    acc[0][1] = mfma16(a0, b1, acc[0][1]);
    acc[1][0] = mfma16(a1, b0, acc[1][0]);
    acc[1][1] = mfma16(a1, b1, acc[1][1]);
  }
  #pragma unroll
  for (int mi = 0; mi < 2; mi++) {
    int mloc = wm + mi * 16 + q * 4;
    int co = (m0 + mloc) >> 3;
    int ph0 = mloc & 7;
    float bias = up_b[co];
    #pragma unroll
    for (int ni = 0; ni < 2; ni++) {
      int n = s0 + ni * 16 + ln;
      f4 v = acc[mi][ni];
      float4 o = make_float4(v[0] + bias, v[1] + bias, v[2] + bias, v[3] + bias);
      *(float4*)(h + ((size_t)b * 64 + co) * OLEN + n * 8 + ph0) = o;
    }
  }
}

// ---------------- kk GEMM (MFMA) v6 (R10 proven config): column-major kern4 ------------
#define KP2 200
__launch_bounds__(256, 3)
__global__ void kk_gemm_mfma(const float* __restrict__ kk_w, const float* __restrict__ kk_b,
                             const ushort* __restrict__ Bim, ushort* __restrict__ kern4) {
  __shared__ ushort As[64 * KP2];      // 25.6 KB, persists whole kernel
  __shared__ ushort Cb[128 * 64];      // 16 KB write bounce
  __shared__ float bias_s[64];
  int m0 = blockIdx.x * 64;
  int layer = blockIdx.y;
  int tid = threadIdx.x;
  if (tid < 64) {
    int m = m0 + tid;
    int ks = m >> 13, co = (m & 8191) >> 6, ci = m & 63;
    bias_s[tid] = kk_b[layer * LROWS + ci * 384 + co * 3 + ks];
  }
  // stage full-K A tile (fp32 -> bf16), row-permuted: m = ks*8192 + co*64 + ci
  for (int i = tid; i < 64 * 48; i += 256) {
    int ml = i / 48, c4 = (i % 48) * 4;
    int m = m0 + ml;
    int ks = m >> 13, co = (m & 8191) >> 6, ci = m & 63;
    int r = ci * 384 + co * 3 + ks;
    float4 v = *(const float4*)(kk_w + ((size_t)layer * LROWS + r) * 192 + c4);
    us4 o = {f2b(v.x), f2b(v.y), f2b(v.z), f2b(v.w)};
    *(us4*)(&As[ml * KP2 + c4]) = o;
  }
  __syncthreads();
  int w = tid >> 6, lane = tid & 63, q = lane >> 4, ln = lane & 15;
  ushort* outp = kern4 + (size_t)layer * 512 * LROWS + m0;
  for (int nc = 0; nc < 4; nc++) {
    int col0 = w * 32;                     // this wave's cols within the chunk
    f4 acc[4][2] = {};
    #pragma unroll
    for (int ks = 0; ks < 6; ks++) {
      int kb = ks * 32 + q * 8;
      bh8 bf[2];
      #pragma unroll
      for (int ni = 0; ni < 2; ni++)
        bf[ni] = *(const bh8*)(Bim + (size_t)(nc * 128 + col0 + ni * 16 + ln) * 192 + kb);
      bh8 af[4];
      #pragma unroll
      for (int mi = 0; mi < 4; mi++)
        af[mi] = *(const bh8*)(&As[(mi * 16 + ln) * KP2 + kb]);
      #pragma unroll
      for (int mi = 0; mi < 4; mi++)
        #pragma unroll
        for (int ni = 0; ni < 2; ni++)
          acc[mi][ni] = mfma16(af[mi], bf[ni], acc[mi][ni]);
    }
    barrier_lgkm();                        // prev Cb read-out done (LDS hazard only)
    #pragma unroll
    for (int ni = 0; ni < 2; ni++) {
      int col = col0 + ni * 16 + ln;
      #pragma unroll
      for (int mi = 0; mi < 4; mi++) {
        f4 bv = *(const f4*)(&bias_s[mi * 16 + q * 4]);
        #pragma unroll
        for (int r = 0; r < 4; r++) {
          int m64 = mi * 16 + q * 4 + r;
          Cb[col * 64 + (((m64 >> 3) ^ (col & 7)) * 8) + (m64 & 7)] = f2b(acc[mi][ni][r] + bv[r]);
        }
      }
    }
    barrier_lgkm();                        // Cb writes visible (LDS hazard only)
    for (int g = tid; g < 1024; g += 256) {
      int col = g >> 3, mc = g & 7;
      us8 v = *(const us8*)(&Cb[col * 64 + ((mc ^ (col & 7)) * 8)]);
      *(us8*)(outp + (size_t)(nc * 128 + col) * LROWS + mc * 8) = v;
    }
  }
}

// ---------------- FUSED conv3(dil) + LVC + gate: 128-t chunks, 256 threads -------------
// Occupancy lever: 44 KB LDS @DIL=27 (38 @DIL=1) -> 3-4 blocks/CU (vs 2 for the 256-t
// chunk version); 1024 blocks -> cross-block phase overlap. Cost: each col's kern4
// As (48 KB) is read by both halves (+24.6 MB/layer, largely L3-served).
template <int DIL>
__launch_bounds__(256, 3)
__global__ void conv_lvc_gate(const float* __restrict__ h_in, const ushort* __restrict__ wct_b,
                              const float* __restrict__ conv_b, const ushort* __restrict__ kern4,
                              const float* __restrict__ bias_all, int layer,
                              float* __restrict__ h_out) {
  // y window: jy in [0,144) <-> t = t0-8+jy  (lvc needs y[t0-1 .. t0+129])
  constexpr int DPAD = ((8 + DIL + 3) / 4) * 4;
  constexpr int ROFF = DPAD - 8 - DIL;
  constexpr int TWP  = ((144 + 2 * DIL + ROFF + 7) / 8) * 8;  // padded h-window rows
  __shared__ ushort HWs[TWP * 64];     // transposed+swizzled lrelu'd h (bf16)
  __shared__ ushort Ys[144 * 64];      // conv output y (post-lrelu), swizzled
  ushort* Asp = HWs;                   // kern4 ks-chunk (16 KB) aliases HWs after conv

  int l = blockIdx.x >> 1;             // 256-t column index (kern4/bias col)
  int b = blockIdx.y;
  int t0 = blockIdx.x * 128;
  int col = b * 128 + l;
  int tid = threadIdx.x;
  const float* hbin = h_in + (size_t)b * 64 * OLEN;

  // ---- phase 1: stage h window (fp32 -> lrelu -> bf16, transposed scatter) ----
  for (int g = tid; g < 64 * (TWP / 4); g += 256) {
    int ci = g / (TWP / 4), jq = g % (TWP / 4);
    int j0 = jq * 4;
    int t = t0 - DPAD + j0;
    const float* src = hbin + (size_t)ci * OLEN + t;
    float4 v = make_float4(0.f, 0.f, 0.f, 0.f);
    if (t >= 0 && t + 4 <= OLEN) {
      v = *(const float4*)src;
    } else {
      if (t + 0 >= 0 && t + 0 < OLEN) v.x = src[0];
      if (t + 1 >= 0 && t + 1 < OLEN) v.y = src[1];
      if (t + 2 >= 0 && t + 2 < OLEN) v.z = src[2];
      if (t + 3 >= 0 && t + 3 < OLEN) v.w = src[3];
    }
    float vv[4] = {v.x, v.y, v.z, v.w};
    #pragma unroll
    for (int k = 0; k < 4; k++) {
      int jj = j0 + k;
      HWs[(jj * 8 + ((ci >> 3) ^ (jj & 7))) * 8 + (ci & 7)] = f2b(lrelu(vv[k], 0.2f));
    }
  }
  __syncthreads();

  int w = tid >> 6, lane = tid & 63, q = lane >> 4, ln = lane & 15;

  // ---- phase 2: conv -> y window [t0-8, t0+136), zero outside [0,OLEN) ----
  for (int tile = w; tile < 9; tile += 4) {
    int jy = tile * 16 + ln;
    f4 a4[4] = {};
    #pragma unroll
    for (int ks = 0; ks < 3; ks++) {
      int jh = jy + ks * DIL + ROFF;
      #pragma unroll
      for (int kst = 0; kst < 2; kst++) {
        bh8 bf = *(const bh8*)(&HWs[(jh * 8 + ((kst * 4 + q) ^ (jh & 7))) * 8]);
        #pragma unroll
        for (int mt = 0; mt < 4; mt++) {
          bh8 a = *(const bh8*)(wct_b + (((layer * 3 + ks) * 64) + mt * 16 + ln) * 64 + kst * 32 + q * 8);
          a4[mt] = mfma16(a, bf, a4[mt]);
        }
      }
    }
    int t = t0 - 8 + jy;
    bool tok = (t >= 0 && t < OLEN);
    #pragma unroll
    for (int mt = 0; mt < 4; mt++) {
      #pragma unroll
      for (int r = 0; r < 4; r++) {
        int co = mt * 16 + q * 4 + r;
        float cb = conv_b[layer * 64 + co];
        ushort v = tok ? f2b(lrelu(a4[mt][r] + cb, 0.2f)) : (ushort)0;
        Ys[(jy * 8 + ((co >> 3) ^ (jy & 7))) * 8 + (co & 7)] = v;
      }
    }
  }

  // ---- phase 3: LVC MFMA (As staged per-ks over dead HWs; column-major kern4) ----
  const ushort* kp = kern4 + ((size_t)layer * 512 + col) * LROWS;
  int n0w = w * 32;
  f4 acc[8][2] = {};
  for (int ks = 0; ks < 3; ks++) {
    __syncthreads();                   // Ys+HWs-reads done (1st) / As reuse (later)
    for (int g = tid; g < 1024; g += 256) {
      us8 v = *(const us8*)(kp + ks * 8192 + g * 8);
      int co = g >> 3, ch = g & 7;
      *(us8*)(&Asp[((g & ~7) | (ch ^ (co & 7))) * 8]) = v;
    }
    __syncthreads();
    #pragma unroll
    for (int kst = 0; kst < 2; kst++) {
      bh8 bfr[2];
      #pragma unroll
      for (int nt = 0; nt < 2; nt++) {
        int j = n0w + nt * 16 + ln + ks;
        int row = j + 7;               // Ys row base is t0-8; y[t0-1+j] = Ys[j+7]
        bfr[nt] = *(const bh8*)(&Ys[(row * 8 + ((kst * 4 + q) ^ (row & 7))) * 8]);
      }
      #pragma unroll
      for (int mt = 0; mt < 8; mt++) {
        int co = mt * 16 + ln;
        bh8 a = *(const bh8*)(&Asp[(co * 8 + ((kst * 4 + q) ^ (co & 7))) * 8]);
        #pragma unroll
        for (int nt = 0; nt < 2; nt++) acc[mt][nt] = mfma16(a, bfr[nt], acc[mt][nt]);
      }
    }
  }

  // ---- phase 4: gate epilogue, h_out = h_in + sig*tanh ----
  float* hbo = h_out + (size_t)b * 64 * OLEN;
  const float* bp = bias_all + (size_t)(b * 512 + layer * 128) * 128 + l;
  #pragma unroll
  for (int mt = 0; mt < 4; mt++) {
    #pragma unroll
    for (int nt = 0; nt < 2; nt++) {
      int t = t0 + n0w + nt * 16 + ln;
      #pragma unroll
      for (int r = 0; r < 4; r++) {
        int co = mt * 16 + q * 4 + r;
        float lo = acc[mt][nt][r] + bp[(size_t)co * 128];
        float hi = acc[mt + 4][nt][r] + bp[(size_t)(co + 64) * 128];
        float sg = __builtin_amdgcn_rcpf(1.f + __expf(-lo));
        float e2 = __expf(-2.f * fabsf(hi));
        float th = __builtin_amdgcn_rcpf(1.f + e2) * (1.f - e2);
        th = copysignf(th, hi);
        hbo[(size_t)co * OLEN + t] = hbin[(size_t)co * OLEN + t] + sg * th;
      }
    }
  }
}

extern "C" void kernel_launch(void* const* d_in, const int* in_sizes, int n_in,
                              void* d_out, int out_size, void* d_ws, size_t ws_size,
                              hipStream_t stream) {
  const float* x      = (const float*)d_in[0];
  const float* c      = (const float*)d_in[1];
  const float* up_w   = (const float*)d_in[2];
  const float* up_b   = (const float*)d_in[3];
  const float* kin_w  = (const float*)d_in[4];
  const float* kin_b  = (const float*)d_in[5];
  const float* kres_w = (const float*)d_in[6];
  const float* kres_b = (const float*)d_in[7];
  const float* kk_w   = (const float*)d_in[8];
  const float* kk_b   = (const float*)d_in[9];
  const float* kb_w   = (const float*)d_in[10];
  const float* kb_b   = (const float*)d_in[11];
  const float* conv_w = (const float*)d_in[12];
  const float* conv_b = (const float*)d_in[13];
  float* h = (float*)d_out;

  float* ws = (float*)d_ws;
  float* hsum     = ws; ws += 4 * 64 * 128;
  float* bias_all = ws; ws += 4 * 512 * 128;
  float* h2       = ws; ws += (size_t)4 * 64 * OLEN;
  ushort* kern4   = (ushort*)ws; ws += (size_t)4 * 512 * LROWS / 2;
  ushort* Bim     = (ushort*)ws; ws += 4 * 128 * 192 / 2;
  ushort* xT      = (ushort*)ws; ws += 4 * 4098 * 64 / 2 + 64;
  ushort* A3      = (ushort*)ws; ws += 512 * 192 / 2;
  ushort* wct_b   = (ushort*)ws; ws += 4 * 3 * 64 * 64 / 2;
  ushort* Ah      = (ushort*)ws; ws += 64 * 480 / 2;
  ushort* Ar      = (ushort*)ws; ws += 6 * 64 * 192 / 2;

  mega_prep<<<936, 256, 0, stream>>>(kin_w, kres_w, conv_w, up_w, x, Ah, Ar, wct_b, A3, xT);
  kp_fused<<<dim3(16, 4), 512, 0, stream>>>(c, Ah, kin_b, Ar, kres_b, hsum, Bim);
  kb_mfma<<<dim3(16, 4), 256, 0, stream>>>(kb_w, kb_b, Bim, bias_all);
  kk_gemm_mfma<<<dim3(384, 4), 256, 0, stream>>>(kk_w, kk_b, Bim, kern4);
  upsample_mfma<<<dim3(128, 4, 4), 256, 0, stream>>>(xT, A3, up_b, h);

  // h ping-pong: d_out -> h2 -> d_out -> h2 -> d_out
  float* hA = h;
  float* hB = h2;
  for (int layer = 0; layer < NLAYERS; layer++) {
    switch (layer) {
      case 0: conv_lvc_gate<1><<<dim3(256, 4), 256, 0, stream>>>(hA, wct_b, conv_b, kern4, bias_all, layer, hB); break;
      case 1: conv_lvc_gate<3><<<dim3(256, 4), 256, 0, stream>>>(hA, wct_b, conv_b, kern4, bias_all, layer, hB); break;
      case 2: conv_lvc_gate<9><<<dim3(256, 4), 256, 0, stream>>>(hA, wct_b, conv_b, kern4, bias_all, layer, hB); break;
      case 3: conv_lvc_gate<27><<<dim3(256, 4), 256, 0, stream>>>(hA, wct_b, conv_b, kern4, bias_all, layer, hB); break;
    }
    float* tmp = hA; hA = hB; hB = tmp;
  }
}

// Round 14
// 416.022 us; speedup vs baseline: 1.0769x; 1.0769x over previous
//
#include <hip/hip_runtime.h>
#include <math.h>

#define CIN 64
#define NLAYERS 4
#define HOP 256
#define ILEN 4096
#define OLEN 32768
#define LROWS 24576   // rows of kk per layer = 64*128*3

typedef unsigned int uint;
typedef unsigned short ushort;
typedef __attribute__((ext_vector_type(8))) short bh8;
typedef __attribute__((ext_vector_type(4))) float f4;
typedef __attribute__((ext_vector_type(8))) unsigned short us8;
typedef __attribute__((ext_vector_type(4))) unsigned short us4;

__device__ __forceinline__ float lrelu(float x, float s) { return x >= 0.f ? x : s * x; }

__device__ __forceinline__ ushort f2b(float f) {       // fp32 -> bf16 (RNE)
  uint u = __float_as_uint(f);
  u = u + 0x7fff + ((u >> 16) & 1);
  return (ushort)(u >> 16);
}
__device__ __forceinline__ float b2f(ushort u) {
  return __uint_as_float(((uint)u) << 16);
}
__device__ __forceinline__ f4 mfma16(bh8 a, bh8 b, f4 c) {
  return __builtin_amdgcn_mfma_f32_16x16x32_bf16(a, b, c, 0, 0, 0);
}

// LDS-only barrier: drains DS ops (lgkmcnt) but lets global loads/stores stay in flight.
__device__ __forceinline__ void barrier_lgkm() {
  asm volatile("s_waitcnt lgkmcnt(0)" ::: "memory");
  __builtin_amdgcn_s_barrier();
  __builtin_amdgcn_sched_barrier(0);
}

// ---------------- mega prep: all weight transposes + xT, one launch ------------
// blocks [0,288): Ah/Ar/wct_b; [288,672): A3; [672,680): retired; [680,936): xT
__global__ void mega_prep(const float* __restrict__ kin_w, const float* __restrict__ kres_w,
                          const float* __restrict__ conv_w, const float* __restrict__ up_w,
                          const float* __restrict__ x,
                          ushort* __restrict__ Ah, ushort* __restrict__ Ar,
                          ushort* __restrict__ wct_b, ushort* __restrict__ A3,
                          ushort* __restrict__ xT) {
  __shared__ float ls[64][65];
  int bid = blockIdx.x, tid = threadIdx.x;
  if (bid < 288) {
    int i = bid * 256 + tid;
    if (i < 64 * 480) {
      int ch = i / 480, k = i % 480, tap = k / 96, cc = k % 96;
      float v = (cc < 80) ? kin_w[(ch * 80 + cc) * 5 + tap] : 0.f;
      Ah[i] = f2b(v);
    }
    if (i < 6 * 64 * 192) {
      int j = i / 12288, r = i % 12288, ch = r / 192, k = r % 192, tap = k >> 6, ci = k & 63;
      Ar[i] = f2b(kres_w[((j * 64 + ch) * 64 + ci) * 3 + tap]);
    }
    if (i < 4 * 3 * 64 * 64) {         // wct_b[l][ks][co][ci]
      int ci = i & 63, r = i >> 6, co = r & 63; r >>= 6; int ks = r % 3, l = r / 3;
      wct_b[i] = f2b(conv_w[((l * 64 + co) * 64 + ci) * 3 + ks]);
    }
  } else if (bid < 672) {
    int i = (bid - 288) * 256 + tid;   // A3[m=co*8+ph][k=(u+1)*64+ci]
    if (i < 512 * 192) {
      int k = i % 192, m = i / 192;
      int co = m >> 3, ph = m & 7;
      int u = k / 64 - 1, ci = k % 64;
      int kk0 = (11 - ph) & 7;
      int off = (ph < 4) ? -1 : 0;
      int tap = u - off;
      float v = 0.f;
      if (tap == 0 || tap == 1) {
        int a = 15 - kk0 - 8 * tap;
        v = up_w[(ci * 64 + co) * 16 + a];
      }
      A3[i] = f2b(v);
    }
  } else if (bid < 680) {
    // retired
  } else {
    int blk = bid - 680, b = blk >> 6, st = blk & 63;   // xT
    int s0 = st * 64;
    int c2 = tid >> 6, s = tid & 63;
    #pragma unroll
    for (int r = 0; r < 16; r++) {
      int ci = r * 4 + c2;
      ls[ci][s] = lrelu(x[((size_t)b * 64 + ci) * ILEN + s0 + s], 0.2f);
    }
    __syncthreads();
    int ci = tid & 63, r2 = tid >> 6;
    #pragma unroll
    for (int r = 0; r < 16; r++) {
      int ss = r * 4 + r2;
      xT[((size_t)b * 4098 + 1 + s0 + ss) * 64 + ci] = f2b(ls[ci][ss]);
    }
    if (st == 0) {
      if (tid < 64) xT[((size_t)b * 4098) * 64 + tid] = 0;
      else if (tid < 128) xT[((size_t)b * 4098 + 4097) * 64 + (tid - 64)] = 0;
    }
  }
}

// ---------------- fused kernel predictor, all-MFMA (unchanged) ----------------
__launch_bounds__(512)
__global__ void kp_fused(const float* __restrict__ c, const ushort* __restrict__ Ah,
                         const float* __restrict__ kin_b, const ushort* __restrict__ Ar,
                         const float* __restrict__ kres_b,
                         float* __restrict__ hsum, ushort* __restrict__ Bim) {
  __shared__ ushort cT[36 * 128];
  __shared__ ushort hT[34 * 64];
  __shared__ ushort aA[34 * 64];
  __shared__ ushort aB[34 * 64];
  int chunk = blockIdx.x, b = blockIdx.y;
  int l0 = chunk * 8;
  int tid = threadIdx.x;
  us8 z = {0, 0, 0, 0, 0, 0, 0, 0};
  for (int g = tid; g < 576; g += 512) *(us8*)(&cT[g * 8]) = z;
  for (int g = tid; g < 272; g += 512) {
    *(us8*)(&hT[g * 8]) = z; *(us8*)(&aA[g * 8]) = z; *(us8*)(&aB[g * 8]) = z;
  }
  __syncthreads();
  for (int g = tid; g < 2880; g += 512) {
    int cc = g / 36, r = g % 36;
    int gl = l0 - 10 + r;
    float v = (gl >= 0 && gl < 128) ? c[(b * 80 + cc) * 128 + gl] : 0.f;
    cT[(r * 16 + ((cc >> 3) ^ (r & 7))) * 8 + (cc & 7)] = f2b(v);
  }
  __syncthreads();
  int w = tid >> 6, lane = tid & 63, q = lane >> 4, ln = lane & 15;
  int mt = w >> 1, nt = w & 1;
  int n = nt * 16 + ln;
  int m0 = mt * 16;
  int gl = l0 - 8 + n;
  bool valid = (gl >= 0 && gl < 128);
  {
    f4 acc = {0.f, 0.f, 0.f, 0.f};
    #pragma unroll
    for (int s = 0; s < 15; s++) {
      int tap = s / 3;
      int chn = (s % 3) * 4 + q;
      bh8 a = *(const bh8*)(Ah + (m0 + ln) * 480 + s * 32 + q * 8);
      int row = n + tap;
      bh8 bf = *(const bh8*)(&cT[(row * 16 + (chn ^ (row & 7))) * 8]);
      acc = mfma16(a, bf, acc);
    }
    us4 o;
    #pragma unroll
    for (int r = 0; r < 4; r++) {
      float v = lrelu(acc[r] + kin_b[m0 + q * 4 + r], 0.1f);
      o[r] = valid ? f2b(v) : (ushort)0;
    }
    int row = n + 1, ch0 = m0 + q * 4;
    int off = (row * 8 + ((ch0 >> 3) ^ (row & 7))) * 8 + (ch0 & 7);
    *(us4*)(&hT[off]) = o;
    *(us4*)(&aA[off]) = o;
  }
  __syncthreads();
  for (int j = 0; j < 6; j++) {
    const ushort* ain = (j & 1) ? aB : aA;
    ushort* aout_ = (j & 1) ? aA : aB;
    f4 acc = {0.f, 0.f, 0.f, 0.f};
    #pragma unroll
    for (int s = 0; s < 6; s++) {
      int tap = s >> 1;
      int chn = (s & 1) * 4 + q;
      bh8 a = *(const bh8*)(Ar + j * 12288 + (m0 + ln) * 192 + s * 32 + q * 8);
      int row = n + tap;
      bh8 bf = *(const bh8*)(&ain[(row * 8 + (chn ^ (row & 7))) * 8]);
      acc = mfma16(a, bf, acc);
    }
    us4 o;
    #pragma unroll
    for (int r = 0; r < 4; r++) {
      float v = lrelu(acc[r] + kres_b[j * 64 + m0 + q * 4 + r], 0.1f);
      o[r] = valid ? f2b(v) : (ushort)0;
    }
    int row = n + 1, ch0 = m0 + q * 4;
    *(us4*)(&aout_[(row * 8 + ((ch0 >> 3) ^ (row & 7))) * 8 + (ch0 & 7)]) = o;
    __syncthreads();
  }
  int tch = tid >> 3, tcl = tid & 7;
  {
    int row = 9 + tcl;
    int off = (row * 8 + ((tch >> 3) ^ (row & 7))) * 8 + (tch & 7);
    hsum[(b * 64 + tch) * 128 + l0 + tcl] = b2f(hT[off]) + b2f(aA[off]);
  }
  {
    ushort* bp = Bim + ((size_t)(b * 128 + l0 + tcl)) * 192 + tch * 3;
    #pragma unroll
    for (int t = 0; t < 3; t++) {
      int row = 8 + tcl + t;
      int off = (row * 8 + ((tch >> 3) ^ (row & 7))) * 8 + (tch & 7);
      bp[t] = f2b(b2f(hT[off]) + b2f(aA[off]));
    }
  }
}

#define KKP 104

// ---------------- bias predictor as MFMA GEMM, widened grid: 64 blocks ----------------
__launch_bounds__(256)
__global__ void kb_mfma(const float* __restrict__ kb_w, const float* __restrict__ kb_b,
                        const ushort* __restrict__ Bim, float* __restrict__ bias_all) {
  __shared__ ushort As[128 * KKP];
  __shared__ ushort Bs[32 * KKP];
  __shared__ float bias_s[128];
  int n0 = blockIdx.x * 32;
  int m0 = blockIdx.y * 128;
  int tid = threadIdx.x;
  if (tid < 128) bias_s[tid] = kb_b[m0 + tid];
  const ushort* Bp = Bim + (size_t)n0 * 192;
  int w = tid >> 6, lane = tid & 63, q = lane >> 4, ln = lane & 15;
  int wm = (w >> 1) * 64, wn = (w & 1) * 16;
  f4 acc[4] = {};
  for (int kc = 0; kc < 2; kc++) {
    int kbase = kc * 96;
    __syncthreads();
    for (int i = tid; i < 128 * 24; i += 256) {
      int ml = i / 24, c4 = (i % 24) * 4;
      float4 v = *(const float4*)(kb_w + (size_t)(m0 + ml) * 192 + kbase + c4);
      us4 o = {f2b(v.x), f2b(v.y), f2b(v.z), f2b(v.w)};
      *(us4*)(&As[ml * KKP + c4]) = o;
    }
    for (int i = tid; i < 32 * 12; i += 256) {
      int n = i / 12, c8 = (i % 12) * 8;
      us8 v = *(const us8*)(Bp + (size_t)n * 192 + kbase + c8);
      *(us8*)(&Bs[n * KKP + c8]) = v;
    }
    __syncthreads();
    #pragma unroll
    for (int ks = 0; ks < 3; ks++) {
      int kb = ks * 32 + q * 8;
      bh8 bf = *(const bh8*)(&Bs[(wn + ln) * KKP + kb]);
      #pragma unroll
      for (int mi = 0; mi < 4; mi++) {
        bh8 af = *(const bh8*)(&As[(wm + mi * 16 + ln) * KKP + kb]);
        acc[mi] = mfma16(af, bf, acc[mi]);
      }
    }
  }
  int col = n0 + wn + ln;
  int b = col >> 7, l = col & 127;
  #pragma unroll
  for (int mi = 0; mi < 4; mi++) {
    #pragma unroll
    for (int r = 0; r < 4; r++) {
      int rloc = wm + mi * 16 + q * 4 + r;
      bias_all[((size_t)(b * 512 + m0 + rloc)) * 128 + l] = acc[mi][r] + bias_s[rloc];
    }
  }
}

// ---------------- upsample as MFMA GEMM (unchanged) ----------------
#define UP_KP 200
__launch_bounds__(256, 2)
__global__ void upsample_mfma(const ushort* __restrict__ xT, const ushort* __restrict__ A3,
                              const float* __restrict__ up_b, float* __restrict__ h) {
  __shared__ ushort As[128 * UP_KP];
  __shared__ ushort Bs[32 * UP_KP];
  int s0 = blockIdx.x * 32;
  int m0 = blockIdx.y * 128;
  int b  = blockIdx.z;
  int tid = threadIdx.x;
  {
    const ushort* src = A3 + (size_t)m0 * 192;
    for (int i = tid; i < 128 * 24; i += 256) {
      int m = i / 24, c8 = (i % 24) * 8;
      us8 v = *(const us8*)(src + (size_t)m * 192 + c8);
      *(us8*)(&As[m * UP_KP + c8]) = v;
    }
  }
  for (int i = tid; i < 32 * 24; i += 256) {
    int n = i / 24, rr = i % 24, u = rr / 8, c8 = (rr % 8) * 8;
    us8 v = *(const us8*)(xT + ((size_t)b * 4098 + s0 + n + u) * 64 + c8);
    *(us8*)(&Bs[n * UP_KP + u * 64 + c8]) = v;
  }
  __syncthreads();
  int w = tid >> 6, lane = tid & 63, q = lane >> 4, ln = lane & 15;
  int wm = w * 32;
  f4 acc[2][2] = {};
  #pragma unroll
  for (int ks = 0; ks < 6; ks++) {
    int kb = ks * 32 + q * 8;
    bh8 a0 = *(const bh8*)(&As[(wm + ln) * UP_KP + kb]);
    bh8 a1 = *(const bh8*)(&As[(wm + 16 + ln) * UP_KP + kb]);
    bh8 b0 = *(const bh8*)(&Bs[ln * UP_KP + kb]);
    bh8 b1 = *(const bh8*)(&Bs[(16 + ln) * UP_KP + kb]);
    acc[0][0] = mfma16(a0, b0, acc[0][0]);
    acc[0][1] = mfma16(a0, b1, acc[0][1]);
    acc[1][0] = mfma16(a1, b0, acc[1][0]);
    acc[1][1] = mfma16(a1, b1, acc[1][1]);
  }
  #pragma unroll
  for (int mi = 0; mi < 2; mi++) {
    int mloc = wm + mi * 16 + q * 4;
    int co = (m0 + mloc) >> 3;
    int ph0 = mloc & 7;
    float bias = up_b[co];
    #pragma unroll
    for (int ni = 0; ni < 2; ni++) {
      int n = s0 + ni * 16 + ln;
      f4 v = acc[mi][ni];
      float4 o = make_float4(v[0] + bias, v[1] + bias, v[2] + bias, v[3] + bias);
      *(float4*)(h + ((size_t)b * 64 + co) * OLEN + n * 8 + ph0) = o;
    }
  }
}

// ---------------- kk GEMM (MFMA) v7: B from L2, LDS bounce, lgkm-only loop barriers ----
// (417.4 us measured config; B register prefetch retained as benched — neutral)
#define KP2 200
__launch_bounds__(256, 3)
__global__ void kk_gemm_mfma(const float* __restrict__ kk_w, const float* __restrict__ kk_b,
                             const ushort* __restrict__ Bim, ushort* __restrict__ kern4) {
  __shared__ ushort As[64 * KP2];      // 25.6 KB, persists whole kernel
  __shared__ ushort Cb[128 * 64];      // 16 KB write bounce
  __shared__ float bias_s[64];
  int m0 = blockIdx.x * 64;
  int layer = blockIdx.y;
  int tid = threadIdx.x;
  if (tid < 64) {
    int m = m0 + tid;
    int ks = m >> 13, co = (m & 8191) >> 6, ci = m & 63;
    bias_s[tid] = kk_b[layer * LROWS + ci * 384 + co * 3 + ks];
  }
  // stage full-K A tile (fp32 -> bf16), row-permuted: m = ks*8192 + co*64 + ci
  for (int i = tid; i < 64 * 48; i += 256) {
    int ml = i / 48, c4 = (i % 48) * 4;
    int m = m0 + ml;
    int ks = m >> 13, co = (m & 8191) >> 6, ci = m & 63;
    int r = ci * 384 + co * 3 + ks;
    float4 v = *(const float4*)(kk_w + ((size_t)layer * LROWS + r) * 192 + c4);
    us4 o = {f2b(v.x), f2b(v.y), f2b(v.z), f2b(v.w)};
    *(us4*)(&As[ml * KP2 + c4]) = o;
  }
  __syncthreads();
  int w = tid >> 6, lane = tid & 63, q = lane >> 4, ln = lane & 15;
  int col0 = w * 32;
  ushort* outp = kern4 + (size_t)layer * 512 * LROWS + m0;
  bh8 bcur[6][2], bnxt[6][2];
  #pragma unroll
  for (int ks = 0; ks < 6; ks++) {
    int kb = ks * 32 + q * 8;
    #pragma unroll
    for (int ni = 0; ni < 2; ni++)
      bcur[ks][ni] = *(const bh8*)(Bim + (size_t)(col0 + ni * 16 + ln) * 192 + kb);
  }
  #pragma unroll
  for (int nc = 0; nc < 4; nc++) {
    f4 acc[4][2] = {};
    #pragma unroll
    for (int ks = 0; ks < 6; ks++) {
      int kb = ks * 32 + q * 8;
      bh8 af[4];
      #pragma unroll
      for (int mi = 0; mi < 4; mi++)
        af[mi] = *(const bh8*)(&As[(mi * 16 + ln) * KP2 + kb]);
      #pragma unroll
      for (int mi = 0; mi < 4; mi++)
        #pragma unroll
        for (int ni = 0; ni < 2; ni++)
          acc[mi][ni] = mfma16(af[mi], bcur[ks][ni], acc[mi][ni]);
    }
    if (nc < 3) {                          // prefetch next chunk's B into registers
      #pragma unroll
      for (int ks = 0; ks < 6; ks++) {
        int kb = ks * 32 + q * 8;
        #pragma unroll
        for (int ni = 0; ni < 2; ni++)
          bnxt[ks][ni] = *(const bh8*)(Bim + (size_t)((nc + 1) * 128 + col0 + ni * 16 + ln) * 192 + kb);
      }
    }
    barrier_lgkm();                        // prev Cb read-out done (LDS hazard only)
    #pragma unroll
    for (int ni = 0; ni < 2; ni++) {
      int col = col0 + ni * 16 + ln;
      #pragma unroll
      for (int mi = 0; mi < 4; mi++) {
        f4 bv = *(const f4*)(&bias_s[mi * 16 + q * 4]);
        #pragma unroll
        for (int r = 0; r < 4; r++) {
          int m64 = mi * 16 + q * 4 + r;
          Cb[col * 64 + (((m64 >> 3) ^ (col & 7)) * 8) + (m64 & 7)] = f2b(acc[mi][ni][r] + bv[r]);
        }
      }
    }
    barrier_lgkm();                        // Cb writes visible (LDS hazard only)
    for (int g = tid; g < 1024; g += 256) {
      int col = g >> 3, mc = g & 7;
      us8 v = *(const us8*)(&Cb[col * 64 + ((mc ^ (col & 7)) * 8)]);
      *(us8*)(outp + (size_t)(nc * 128 + col) * LROWS + mc * 8) = v;
    }
    if (nc < 3) {
      #pragma unroll
      for (int ks = 0; ks < 6; ks++)
        #pragma unroll
        for (int ni = 0; ni < 2; ni++)
          bcur[ks][ni] = bnxt[ks][ni];
    }
  }
}

// ---------------- FUSED conv3(dil) + LVC + gate, per layer (417.4 us config) -----------
// Block = one 256-t chunk of one batch, 512 threads, direct transposed scatter staging.
template <int DIL>
__launch_bounds__(512, 4)
__global__ void conv_lvc_gate(const float* __restrict__ h_in, const ushort* __restrict__ wct_b,
                              const float* __restrict__ conv_b, const ushort* __restrict__ kern4,
                              const float* __restrict__ bias_all, int layer,
                              float* __restrict__ h_out) {
  constexpr int DPAD = ((8 + DIL + 3) / 4) * 4;
  constexpr int ROFF = DPAD - 8 - DIL;
  constexpr int TWP  = ((272 + 2 * DIL + ROFF + 7) / 8) * 8;  // padded rows
  __shared__ ushort HWs[TWP * 64];     // transposed+swizzled lrelu'd h (bf16)
  __shared__ ushort Ys[272 * 64];      // conv output y (post-lrelu), swizzled
  ushort* Asp = HWs;                   // kern4 ks-chunk aliases HWs after conv

  int l = blockIdx.x, b = blockIdx.y;
  int t0 = l * 256;
  int col = b * 128 + l;
  int tid = threadIdx.x;
  const float* hbin = h_in + (size_t)b * 64 * OLEN;

  // ---- phase 1: stage h window (fp32 -> lrelu -> bf16, transposed scatter) ----
  for (int g = tid; g < 64 * (TWP / 4); g += 512) {
    int ci = g / (TWP / 4), jq = g % (TWP / 4);
    int j0 = jq * 4;
    int t = t0 - DPAD + j0;
    const float* src = hbin + (size_t)ci * OLEN + t;
    float4 v = make_float4(0.f, 0.f, 0.f, 0.f);
    if (t >= 0 && t + 4 <= OLEN) {
      v = *(const float4*)src;
    } else {
      if (t + 0 >= 0 && t + 0 < OLEN) v.x = src[0];
      if (t + 1 >= 0 && t + 1 < OLEN) v.y = src[1];
      if (t + 2 >= 0 && t + 2 < OLEN) v.z = src[2];
      if (t + 3 >= 0 && t + 3 < OLEN) v.w = src[3];
    }
    float vv[4] = {v.x, v.y, v.z, v.w};
    #pragma unroll
    for (int k = 0; k < 4; k++) {
      int jj = j0 + k;
      HWs[(jj * 8 + ((ci >> 3) ^ (jj & 7))) * 8 + (ci & 7)] = f2b(lrelu(vv[k], 0.2f));
    }
  }
  __syncthreads();

  int w = tid >> 6, lane = tid & 63, q = lane >> 4, ln = lane & 15;

  // ---- phase 2: conv -> y window [t0-8, t0+264), zero outside [0,OLEN) ----
  for (int tile = w; tile < 17; tile += 8) {
    int jy = tile * 16 + ln;
    f4 a4[4] = {};
    #pragma unroll
    for (int ks = 0; ks < 3; ks++) {
      int jh = jy + ks * DIL + ROFF;
      #pragma unroll
      for (int kst = 0; kst < 2; kst++) {
        bh8 bf = *(const bh8*)(&HWs[(jh * 8 + ((kst * 4 + q) ^ (jh & 7))) * 8]);
        #pragma unroll
        for (int mt = 0; mt < 4; mt++) {
          bh8 a = *(const bh8*)(wct_b + (((layer * 3 + ks) * 64) + mt * 16 + ln) * 64 + kst * 32 + q * 8);
          a4[mt] = mfma16(a, bf, a4[mt]);
        }
      }
    }
    int t = t0 - 8 + jy;
    bool tok = (t >= 0 && t < OLEN);
    #pragma unroll
    for (int mt = 0; mt < 4; mt++) {
      #pragma unroll
      for (int r = 0; r < 4; r++) {
        int co = mt * 16 + q * 4 + r;
        float cb = conv_b[layer * 64 + co];
        ushort v = tok ? f2b(lrelu(a4[mt][r] + cb, 0.2f)) : (ushort)0;
        Ys[(jy * 8 + ((co >> 3) ^ (jy & 7))) * 8 + (co & 7)] = v;
      }
    }
  }

  // ---- phase 3: LVC MFMA (As staged per-ks over dead HWs) ----
  const ushort* kp = kern4 + ((size_t)layer * 512 + col) * LROWS;
  int n0w = w * 32;
  f4 acc[8][2] = {};
  for (int ks = 0; ks < 3; ks++) {
    __syncthreads();                   // Ys+HWs-reads done (1st) / As reuse (later)
    for (int g = tid; g < 1024; g += 512) {
      us8 v = *(const us8*)(kp + ks * 8192 + g * 8);
      int co = g >> 3, ch = g & 7;
      *(us8*)(&Asp[((g & ~7) | (ch ^ (co & 7))) * 8]) = v;
    }
    __syncthreads();
    #pragma unroll
    for (int kst = 0; kst < 2; kst++) {
      bh8 bfr[2];
      #pragma unroll
      for (int nt = 0; nt < 2; nt++) {
        int j = n0w + nt * 16 + ln + ks;
        int row = j + 7;               // Ys row base is t0-8; y[t0-1+j] = Ys[j+7]
        bfr[nt] = *(const bh8*)(&Ys[(row * 8 + ((kst * 4 + q) ^ (row & 7))) * 8]);
      }
      #pragma unroll
      for (int mt = 0; mt < 8; mt++) {
        int co = mt * 16 + ln;
        bh8 a = *(const bh8*)(&Asp[(co * 8 + ((kst * 4 + q) ^ (co & 7))) * 8]);
        #pragma unroll
        for (int nt = 0; nt < 2; nt++) acc[mt][nt] = mfma16(a, bfr[nt], acc[mt][nt]);
      }
    }
  }

  // ---- phase 4: gate epilogue, h_out = h_in + sig*tanh ----
  float* hbo = h_out + (size_t)b * 64 * OLEN;
  const float* bp = bias_all + (size_t)(b * 512 + layer * 128) * 128 + l;
  #pragma unroll
  for (int mt = 0; mt < 4; mt++) {
    #pragma unroll
    for (int nt = 0; nt < 2; nt++) {
      int t = t0 + n0w + nt * 16 + ln;
      #pragma unroll
      for (int r = 0; r < 4; r++) {
        int co = mt * 16 + q * 4 + r;
        float lo = acc[mt][nt][r] + bp[(size_t)co * 128];
        float hi = acc[mt + 4][nt][r] + bp[(size_t)(co + 64) * 128];
        float sg = __builtin_amdgcn_rcpf(1.f + __expf(-lo));
        float e2 = __expf(-2.f * fabsf(hi));
        float th = __builtin_amdgcn_rcpf(1.f + e2) * (1.f - e2);
        th = copysignf(th, hi);
        hbo[(size_t)co * OLEN + t] = hbin[(size_t)co * OLEN + t] + sg * th;
      }
    }
  }
}

extern "C" void kernel_launch(void* const* d_in, const int* in_sizes, int n_in,
                              void* d_out, int out_size, void* d_ws, size_t ws_size,
                              hipStream_t stream) {
  const float* x      = (const float*)d_in[0];
  const float* c      = (const float*)d_in[1];
  const float* up_w   = (const float*)d_in[2];
  const float* up_b   = (const float*)d_in[3];
  const float* kin_w  = (const float*)d_in[4];
  const float* kin_b  = (const float*)d_in[5];
  const float* kres_w = (const float*)d_in[6];
  const float* kres_b = (const float*)d_in[7];
  const float* kk_w   = (const float*)d_in[8];
  const float* kk_b   = (const float*)d_in[9];
  const float* kb_w   = (const float*)d_in[10];
  const float* kb_b   = (const float*)d_in[11];
  const float* conv_w = (const float*)d_in[12];
  const float* conv_b = (const float*)d_in[13];
  float* h = (float*)d_out;

  float* ws = (float*)d_ws;
  float* hsum     = ws; ws += 4 * 64 * 128;
  float* bias_all = ws; ws += 4 * 512 * 128;
  float* h2       = ws; ws += (size_t)4 * 64 * OLEN;
  ushort* kern4   = (ushort*)ws; ws += (size_t)4 * 512 * LROWS / 2;
  ushort* Bim     = (ushort*)ws; ws += 4 * 128 * 192 / 2;
  ushort* xT      = (ushort*)ws; ws += 4 * 4098 * 64 / 2 + 64;
  ushort* A3      = (ushort*)ws; ws += 512 * 192 / 2;
  ushort* wct_b   = (ushort*)ws; ws += 4 * 3 * 64 * 64 / 2;
  ushort* Ah      = (ushort*)ws; ws += 64 * 480 / 2;
  ushort* Ar      = (ushort*)ws; ws += 6 * 64 * 192 / 2;

  mega_prep<<<936, 256, 0, stream>>>(kin_w, kres_w, conv_w, up_w, x, Ah, Ar, wct_b, A3, xT);
  kp_fused<<<dim3(16, 4), 512, 0, stream>>>(c, Ah, kin_b, Ar, kres_b, hsum, Bim);
  kb_mfma<<<dim3(16, 4), 256, 0, stream>>>(kb_w, kb_b, Bim, bias_all);
  kk_gemm_mfma<<<dim3(384, 4), 256, 0, stream>>>(kk_w, kk_b, Bim, kern4);
  upsample_mfma<<<dim3(128, 4, 4), 256, 0, stream>>>(xT, A3, up_b, h);

  // h ping-pong: d_out -> h2 -> d_out -> h2 -> d_out
  float* hA = h;
  float* hB = h2;
  for (int layer = 0; layer < NLAYERS; layer++) {
    switch (layer) {
      case 0: conv_lvc_gate<1><<<dim3(128, 4), 512, 0, stream>>>(hA, wct_b, conv_b, kern4, bias_all, layer, hB); break;
      case 1: conv_lvc_gate<3><<<dim3(128, 4), 512, 0, stream>>>(hA, wct_b, conv_b, kern4, bias_all, layer, hB); break;
      case 2: conv_lvc_gate<9><<<dim3(128, 4), 512, 0, stream>>>(hA, wct_b, conv_b, kern4, bias_all, layer, hB); break;
      case 3: conv_lvc_gate<27><<<dim3(128, 4), 512, 0, stream>>>(hA, wct_b, conv_b, kern4, bias_all, layer, hB); break;
    }
    float* tmp = hA; hA = hB; hB = tmp;
  }
}

// Round 15
// 411.696 us; speedup vs baseline: 1.0882x; 1.0105x over previous
//
#include <hip/hip_runtime.h>
#include <math.h>

#define CIN 64
#define NLAYERS 4
#define HOP 256
#define ILEN 4096
#define OLEN 32768
#define LROWS 24576   // rows of kk per layer = 64*128*3

typedef unsigned int uint;
typedef unsigned short ushort;
typedef __attribute__((ext_vector_type(8))) short bh8;
typedef __attribute__((ext_vector_type(4))) float f4;
typedef __attribute__((ext_vector_type(8))) unsigned short us8;
typedef __attribute__((ext_vector_type(4))) unsigned short us4;

__device__ __forceinline__ float lrelu(float x, float s) { return x >= 0.f ? x : s * x; }

__device__ __forceinline__ ushort f2b(float f) {       // fp32 -> bf16 (RNE)
  uint u = __float_as_uint(f);
  u = u + 0x7fff + ((u >> 16) & 1);
  return (ushort)(u >> 16);
}
__device__ __forceinline__ float b2f(ushort u) {
  return __uint_as_float(((uint)u) << 16);
}
__device__ __forceinline__ f4 mfma16(bh8 a, bh8 b, f4 c) {
  return __builtin_amdgcn_mfma_f32_16x16x32_bf16(a, b, c, 0, 0, 0);
}

// LDS-only barrier: drains DS ops (lgkmcnt) but lets global loads/stores stay in flight.
__device__ __forceinline__ void barrier_lgkm() {
  asm volatile("s_waitcnt lgkmcnt(0)" ::: "memory");
  __builtin_amdgcn_s_barrier();
  __builtin_amdgcn_sched_barrier(0);
}

// ---------------- mega prep: all weight transposes + xT, one launch ------------
// blocks [0,288): Ah/Ar/wct_b; [288,672): A3; [672,680): retired; [680,936): xT
__global__ void mega_prep(const float* __restrict__ kin_w, const float* __restrict__ kres_w,
                          const float* __restrict__ conv_w, const float* __restrict__ up_w,
                          const float* __restrict__ x,
                          ushort* __restrict__ Ah, ushort* __restrict__ Ar,
                          ushort* __restrict__ wct_b, ushort* __restrict__ A3,
                          ushort* __restrict__ xT) {
  __shared__ float ls[64][65];
  int bid = blockIdx.x, tid = threadIdx.x;
  if (bid < 288) {
    int i = bid * 256 + tid;
    if (i < 64 * 480) {
      int ch = i / 480, k = i % 480, tap = k / 96, cc = k % 96;
      float v = (cc < 80) ? kin_w[(ch * 80 + cc) * 5 + tap] : 0.f;
      Ah[i] = f2b(v);
    }
    if (i < 6 * 64 * 192) {
      int j = i / 12288, r = i % 12288, ch = r / 192, k = r % 192, tap = k >> 6, ci = k & 63;
      Ar[i] = f2b(kres_w[((j * 64 + ch) * 64 + ci) * 3 + tap]);
    }
    if (i < 4 * 3 * 64 * 64) {         // wct_b[l][ks][co][ci]
      int ci = i & 63, r = i >> 6, co = r & 63; r >>= 6; int ks = r % 3, l = r / 3;
      wct_b[i] = f2b(conv_w[((l * 64 + co) * 64 + ci) * 3 + ks]);
    }
  } else if (bid < 672) {
    int i = (bid - 288) * 256 + tid;   // A3[m=co*8+ph][k=(u+1)*64+ci]
    if (i < 512 * 192) {
      int k = i % 192, m = i / 192;
      int co = m >> 3, ph = m & 7;
      int u = k / 64 - 1, ci = k % 64;
      int kk0 = (11 - ph) & 7;
      int off = (ph < 4) ? -1 : 0;
      int tap = u - off;
      float v = 0.f;
      if (tap == 0 || tap == 1) {
        int a = 15 - kk0 - 8 * tap;
        v = up_w[(ci * 64 + co) * 16 + a];
      }
      A3[i] = f2b(v);
    }
  } else if (bid < 680) {
    // retired
  } else {
    int blk = bid - 680, b = blk >> 6, st = blk & 63;   // xT
    int s0 = st * 64;
    int c2 = tid >> 6, s = tid & 63;
    #pragma unroll
    for (int r = 0; r < 16; r++) {
      int ci = r * 4 + c2;
      ls[ci][s] = lrelu(x[((size_t)b * 64 + ci) * ILEN + s0 + s], 0.2f);
    }
    __syncthreads();
    int ci = tid & 63, r2 = tid >> 6;
    #pragma unroll
    for (int r = 0; r < 16; r++) {
      int ss = r * 4 + r2;
      xT[((size_t)b * 4098 + 1 + s0 + ss) * 64 + ci] = f2b(ls[ci][ss]);
    }
    if (st == 0) {
      if (tid < 64) xT[((size_t)b * 4098) * 64 + tid] = 0;
      else if (tid < 128) xT[((size_t)b * 4098 + 4097) * 64 + (tid - 64)] = 0;
    }
  }
}

// ---------------- fused kernel predictor, all-MFMA (unchanged) ----------------
__launch_bounds__(512)
__global__ void kp_fused(const float* __restrict__ c, const ushort* __restrict__ Ah,
                         const float* __restrict__ kin_b, const ushort* __restrict__ Ar,
                         const float* __restrict__ kres_b,
                         float* __restrict__ hsum, ushort* __restrict__ Bim) {
  __shared__ ushort cT[36 * 128];
  __shared__ ushort hT[34 * 64];
  __shared__ ushort aA[34 * 64];
  __shared__ ushort aB[34 * 64];
  int chunk = blockIdx.x, b = blockIdx.y;
  int l0 = chunk * 8;
  int tid = threadIdx.x;
  us8 z = {0, 0, 0, 0, 0, 0, 0, 0};
  for (int g = tid; g < 576; g += 512) *(us8*)(&cT[g * 8]) = z;
  for (int g = tid; g < 272; g += 512) {
    *(us8*)(&hT[g * 8]) = z; *(us8*)(&aA[g * 8]) = z; *(us8*)(&aB[g * 8]) = z;
  }
  __syncthreads();
  for (int g = tid; g < 2880; g += 512) {
    int cc = g / 36, r = g % 36;
    int gl = l0 - 10 + r;
    float v = (gl >= 0 && gl < 128) ? c[(b * 80 + cc) * 128 + gl] : 0.f;
    cT[(r * 16 + ((cc >> 3) ^ (r & 7))) * 8 + (cc & 7)] = f2b(v);
  }
  __syncthreads();
  int w = tid >> 6, lane = tid & 63, q = lane >> 4, ln = lane & 15;
  int mt = w >> 1, nt = w & 1;
  int n = nt * 16 + ln;
  int m0 = mt * 16;
  int gl = l0 - 8 + n;
  bool valid = (gl >= 0 && gl < 128);
  {
    f4 acc = {0.f, 0.f, 0.f, 0.f};
    #pragma unroll
    for (int s = 0; s < 15; s++) {
      int tap = s / 3;
      int chn = (s % 3) * 4 + q;
      bh8 a = *(const bh8*)(Ah + (m0 + ln) * 480 + s * 32 + q * 8);
      int row = n + tap;
      bh8 bf = *(const bh8*)(&cT[(row * 16 + (chn ^ (row & 7))) * 8]);
      acc = mfma16(a, bf, acc);
    }
    us4 o;
    #pragma unroll
    for (int r = 0; r < 4; r++) {
      float v = lrelu(acc[r] + kin_b[m0 + q * 4 + r], 0.1f);
      o[r] = valid ? f2b(v) : (ushort)0;
    }
    int row = n + 1, ch0 = m0 + q * 4;
    int off = (row * 8 + ((ch0 >> 3) ^ (row & 7))) * 8 + (ch0 & 7);
    *(us4*)(&hT[off]) = o;
    *(us4*)(&aA[off]) = o;
  }
  __syncthreads();
  for (int j = 0; j < 6; j++) {
    const ushort* ain = (j & 1) ? aB : aA;
    ushort* aout_ = (j & 1) ? aA : aB;
    f4 acc = {0.f, 0.f, 0.f, 0.f};
    #pragma unroll
    for (int s = 0; s < 6; s++) {
      int tap = s >> 1;
      int chn = (s & 1) * 4 + q;
      bh8 a = *(const bh8*)(Ar + j * 12288 + (m0 + ln) * 192 + s * 32 + q * 8);
      int row = n + tap;
      bh8 bf = *(const bh8*)(&ain[(row * 8 + (chn ^ (row & 7))) * 8]);
      acc = mfma16(a, bf, acc);
    }
    us4 o;
    #pragma unroll
    for (int r = 0; r < 4; r++) {
      float v = lrelu(acc[r] + kres_b[j * 64 + m0 + q * 4 + r], 0.1f);
      o[r] = valid ? f2b(v) : (ushort)0;
    }
    int row = n + 1, ch0 = m0 + q * 4;
    *(us4*)(&aout_[(row * 8 + ((ch0 >> 3) ^ (row & 7))) * 8 + (ch0 & 7)]) = o;
    __syncthreads();
  }
  int tch = tid >> 3, tcl = tid & 7;
  {
    int row = 9 + tcl;
    int off = (row * 8 + ((tch >> 3) ^ (row & 7))) * 8 + (tch & 7);
    hsum[(b * 64 + tch) * 128 + l0 + tcl] = b2f(hT[off]) + b2f(aA[off]);
  }
  {
    ushort* bp = Bim + ((size_t)(b * 128 + l0 + tcl)) * 192 + tch * 3;
    #pragma unroll
    for (int t = 0; t < 3; t++) {
      int row = 8 + tcl + t;
      int off = (row * 8 + ((tch >> 3) ^ (row & 7))) * 8 + (tch & 7);
      bp[t] = f2b(b2f(hT[off]) + b2f(aA[off]));
    }
  }
}

#define KKP 104
#define KP2 200

// ---------------- mid-pipeline horizontal fusion: kk + kb + upsample -------------------
// All three are independent (inputs: Bim / xT / A3, all ready after kp_fused) but were
// serialized on the stream. One dispatch lets the scheduler co-residence kk's
// latency-bound blocks with kb/upsample's BW-bound blocks. Union LDS = kk's 42.2 KB
// (upsample retiled to 64-row m-tiles to fit) -> 3 blocks/CU for every branch.
// Per y-slice: x<384 kk | x<400 kb | x<1424 upsample (order interleaves branches).
__launch_bounds__(256, 3)
__global__ void mid_fused(const float* __restrict__ kk_w, const float* __restrict__ kk_b,
                          const ushort* __restrict__ Bim, ushort* __restrict__ kern4,
                          const float* __restrict__ kb_w, const float* __restrict__ kb_b,
                          float* __restrict__ bias_all,
                          const ushort* __restrict__ xT, const ushort* __restrict__ A3,
                          const float* __restrict__ up_b, float* __restrict__ h) {
  __shared__ __align__(16) ushort smem[21120];   // 42240 B union
  int bx = blockIdx.x, by = blockIdx.y;
  int tid = threadIdx.x;
  int w = tid >> 6, lane = tid & 63, q = lane >> 4, ln = lane & 15;

  if (bx < 384) {
    // ================= kk GEMM branch (v7, unchanged body) =================
    ushort* As = smem;                         // 64*200
    ushort* Cb = smem + 64 * KP2;              // 128*64
    float* bias_s = (float*)(smem + 64 * KP2 + 128 * 64);   // 64 floats
    int m0 = bx * 64;
    int layer = by;
    if (tid < 64) {
      int m = m0 + tid;
      int ks = m >> 13, co = (m & 8191) >> 6, ci = m & 63;
      bias_s[tid] = kk_b[layer * LROWS + ci * 384 + co * 3 + ks];
    }
    for (int i = tid; i < 64 * 48; i += 256) {
      int ml = i / 48, c4 = (i % 48) * 4;
      int m = m0 + ml;
      int ks = m >> 13, co = (m & 8191) >> 6, ci = m & 63;
      int r = ci * 384 + co * 3 + ks;
      float4 v = *(const float4*)(kk_w + ((size_t)layer * LROWS + r) * 192 + c4);
      us4 o = {f2b(v.x), f2b(v.y), f2b(v.z), f2b(v.w)};
      *(us4*)(&As[ml * KP2 + c4]) = o;
    }
    __syncthreads();
    int col0 = w * 32;
    ushort* outp = kern4 + (size_t)layer * 512 * LROWS + m0;
    bh8 bcur[6][2], bnxt[6][2];
    #pragma unroll
    for (int ks = 0; ks < 6; ks++) {
      int kb = ks * 32 + q * 8;
      #pragma unroll
      for (int ni = 0; ni < 2; ni++)
        bcur[ks][ni] = *(const bh8*)(Bim + (size_t)(col0 + ni * 16 + ln) * 192 + kb);
    }
    #pragma unroll
    for (int nc = 0; nc < 4; nc++) {
      f4 acc[4][2] = {};
      #pragma unroll
      for (int ks = 0; ks < 6; ks++) {
        int kb = ks * 32 + q * 8;
        bh8 af[4];
        #pragma unroll
        for (int mi = 0; mi < 4; mi++)
          af[mi] = *(const bh8*)(&As[(mi * 16 + ln) * KP2 + kb]);
        #pragma unroll
        for (int mi = 0; mi < 4; mi++)
          #pragma unroll
          for (int ni = 0; ni < 2; ni++)
            acc[mi][ni] = mfma16(af[mi], bcur[ks][ni], acc[mi][ni]);
      }
      if (nc < 3) {
        #pragma unroll
        for (int ks = 0; ks < 6; ks++) {
          int kb = ks * 32 + q * 8;
          #pragma unroll
          for (int ni = 0; ni < 2; ni++)
            bnxt[ks][ni] = *(const bh8*)(Bim + (size_t)((nc + 1) * 128 + col0 + ni * 16 + ln) * 192 + kb);
        }
      }
      barrier_lgkm();
      #pragma unroll
      for (int ni = 0; ni < 2; ni++) {
        int col = col0 + ni * 16 + ln;
        #pragma unroll
        for (int mi = 0; mi < 4; mi++) {
          f4 bv = *(const f4*)(&bias_s[mi * 16 + q * 4]);
          #pragma unroll
          for (int r = 0; r < 4; r++) {
            int m64 = mi * 16 + q * 4 + r;
            Cb[col * 64 + (((m64 >> 3) ^ (col & 7)) * 8) + (m64 & 7)] = f2b(acc[mi][ni][r] + bv[r]);
          }
        }
      }
      barrier_lgkm();
      for (int g = tid; g < 1024; g += 256) {
        int col = g >> 3, mc = g & 7;
        us8 v = *(const us8*)(&Cb[col * 64 + ((mc ^ (col & 7)) * 8)]);
        *(us8*)(outp + (size_t)(nc * 128 + col) * LROWS + mc * 8) = v;
      }
      if (nc < 3) {
        #pragma unroll
        for (int ks = 0; ks < 6; ks++)
          #pragma unroll
          for (int ni = 0; ni < 2; ni++)
            bcur[ks][ni] = bnxt[ks][ni];
      }
    }
  } else if (bx < 400) {
    // ================= kb branch (unchanged body) =================
    ushort* As = smem;                         // 128*104
    ushort* Bs = smem + 128 * KKP;             // 32*104
    float* bias_s = (float*)(smem + 128 * KKP + 32 * KKP);  // 128 floats
    int n0 = (bx - 384) * 32;
    int m0 = by * 128;
    if (tid < 128) bias_s[tid] = kb_b[m0 + tid];
    const ushort* Bp = Bim + (size_t)n0 * 192;
    int wm = (w >> 1) * 64, wn = (w & 1) * 16;
    f4 acc[4] = {};
    for (int kc = 0; kc < 2; kc++) {
      int kbase = kc * 96;
      __syncthreads();
      for (int i = tid; i < 128 * 24; i += 256) {
        int ml = i / 24, c4 = (i % 24) * 4;
        float4 v = *(const float4*)(kb_w + (size_t)(m0 + ml) * 192 + kbase + c4);
        us4 o = {f2b(v.x), f2b(v.y), f2b(v.z), f2b(v.w)};
        *(us4*)(&As[ml * KKP + c4]) = o;
      }
      for (int i = tid; i < 32 * 12; i += 256) {
        int n = i / 12, c8 = (i % 12) * 8;
        us8 v = *(const us8*)(Bp + (size_t)n * 192 + kbase + c8);
        *(us8*)(&Bs[n * KKP + c8]) = v;
      }
      __syncthreads();
      #pragma unroll
      for (int ks = 0; ks < 3; ks++) {
        int kb = ks * 32 + q * 8;
        bh8 bf = *(const bh8*)(&Bs[(wn + ln) * KKP + kb]);
        #pragma unroll
        for (int mi = 0; mi < 4; mi++) {
          bh8 af = *(const bh8*)(&As[(wm + mi * 16 + ln) * KKP + kb]);
          acc[mi] = mfma16(af, bf, acc[mi]);
        }
      }
    }
    int col = n0 + wn + ln;
    int b = col >> 7, l = col & 127;
    #pragma unroll
    for (int mi = 0; mi < 4; mi++) {
      #pragma unroll
      for (int r = 0; r < 4; r++) {
        int rloc = wm + mi * 16 + q * 4 + r;
        bias_all[((size_t)(b * 512 + m0 + rloc)) * 128 + l] = acc[mi][r] + bias_s[rloc];
      }
    }
  } else {
    // ================= upsample branch (64-row m-tiles) =================
    ushort* As = smem;                         // 64*200
    ushort* Bs = smem + 64 * KP2;              // 32*200
    int u = bx - 400;
    int s0 = (u & 127) * 32;
    int m0 = (u >> 7) * 64;
    int b  = by;
    {
      const ushort* src = A3 + (size_t)m0 * 192;
      for (int i = tid; i < 64 * 24; i += 256) {
        int m = i / 24, c8 = (i % 24) * 8;
        us8 v = *(const us8*)(src + (size_t)m * 192 + c8);
        *(us8*)(&As[m * KP2 + c8]) = v;
      }
    }
    for (int i = tid; i < 32 * 24; i += 256) {
      int n = i / 24, rr = i % 24, uu = rr / 8, c8 = (rr % 8) * 8;
      us8 v = *(const us8*)(xT + ((size_t)b * 4098 + s0 + n + uu) * 64 + c8);
      *(us8*)(&Bs[n * KP2 + uu * 64 + c8]) = v;
    }
    __syncthreads();
    int wm = w * 16;
    f4 acc0 = {}, acc1 = {};
    #pragma unroll
    for (int ks = 0; ks < 6; ks++) {
      int kb = ks * 32 + q * 8;
      bh8 a0 = *(const bh8*)(&As[(wm + ln) * KP2 + kb]);
      bh8 b0 = *(const bh8*)(&Bs[ln * KP2 + kb]);
      bh8 b1 = *(const bh8*)(&Bs[(16 + ln) * KP2 + kb]);
      acc0 = mfma16(a0, b0, acc0);
      acc1 = mfma16(a0, b1, acc1);
    }
    int mloc = wm + q * 4;
    int co = (m0 + mloc) >> 3;
    int ph0 = mloc & 7;
    float bias = up_b[co];
    {
      int n = s0 + ln;
      float4 o = make_float4(acc0[0] + bias, acc0[1] + bias, acc0[2] + bias, acc0[3] + bias);
      *(float4*)(h + ((size_t)b * 64 + co) * OLEN + n * 8 + ph0) = o;
    }
    {
      int n = s0 + 16 + ln;
      float4 o = make_float4(acc1[0] + bias, acc1[1] + bias, acc1[2] + bias, acc1[3] + bias);
      *(float4*)(h + ((size_t)b * 64 + co) * OLEN + n * 8 + ph0) = o;
    }
  }
}

// ---------------- FUSED conv3(dil) + LVC + gate, per layer (417.4 us config) -----------
// Block = one 256-t chunk of one batch, 512 threads, direct transposed scatter staging.
template <int DIL>
__launch_bounds__(512, 4)
__global__ void conv_lvc_gate(const float* __restrict__ h_in, const ushort* __restrict__ wct_b,
                              const float* __restrict__ conv_b, const ushort* __restrict__ kern4,
                              const float* __restrict__ bias_all, int layer,
                              float* __restrict__ h_out) {
  constexpr int DPAD = ((8 + DIL + 3) / 4) * 4;
  constexpr int ROFF = DPAD - 8 - DIL;
  constexpr int TWP  = ((272 + 2 * DIL + ROFF + 7) / 8) * 8;  // padded rows
  __shared__ ushort HWs[TWP * 64];     // transposed+swizzled lrelu'd h (bf16)
  __shared__ ushort Ys[272 * 64];      // conv output y (post-lrelu), swizzled
  ushort* Asp = HWs;                   // kern4 ks-chunk aliases HWs after conv

  int l = blockIdx.x, b = blockIdx.y;
  int t0 = l * 256;
  int col = b * 128 + l;
  int tid = threadIdx.x;
  const float* hbin = h_in + (size_t)b * 64 * OLEN;

  // ---- phase 1: stage h window (fp32 -> lrelu -> bf16, transposed scatter) ----
  for (int g = tid; g < 64 * (TWP / 4); g += 512) {
    int ci = g / (TWP / 4), jq = g % (TWP / 4);
    int j0 = jq * 4;
    int t = t0 - DPAD + j0;
    const float* src = hbin + (size_t)ci * OLEN + t;
    float4 v = make_float4(0.f, 0.f, 0.f, 0.f);
    if (t >= 0 && t + 4 <= OLEN) {
      v = *(const float4*)src;
    } else {
      if (t + 0 >= 0 && t + 0 < OLEN) v.x = src[0];
      if (t + 1 >= 0 && t + 1 < OLEN) v.y = src[1];
      if (t + 2 >= 0 && t + 2 < OLEN) v.z = src[2];
      if (t + 3 >= 0 && t + 3 < OLEN) v.w = src[3];
    }
    float vv[4] = {v.x, v.y, v.z, v.w};
    #pragma unroll
    for (int k = 0; k < 4; k++) {
      int jj = j0 + k;
      HWs[(jj * 8 + ((ci >> 3) ^ (jj & 7))) * 8 + (ci & 7)] = f2b(lrelu(vv[k], 0.2f));
    }
  }
  __syncthreads();

  int w = tid >> 6, lane = tid & 63, q = lane >> 4, ln = lane & 15;

  // ---- phase 2: conv -> y window [t0-8, t0+264), zero outside [0,OLEN) ----
  for (int tile = w; tile < 17; tile += 8) {
    int jy = tile * 16 + ln;
    f4 a4[4] = {};
    #pragma unroll
    for (int ks = 0; ks < 3; ks++) {
      int jh = jy + ks * DIL + ROFF;
      #pragma unroll
      for (int kst = 0; kst < 2; kst++) {
        bh8 bf = *(const bh8*)(&HWs[(jh * 8 + ((kst * 4 + q) ^ (jh & 7))) * 8]);
        #pragma unroll
        for (int mt = 0; mt < 4; mt++) {
          bh8 a = *(const bh8*)(wct_b + (((layer * 3 + ks) * 64) + mt * 16 + ln) * 64 + kst * 32 + q * 8);
          a4[mt] = mfma16(a, bf, a4[mt]);
        }
      }
    }
    int t = t0 - 8 + jy;
    bool tok = (t >= 0 && t < OLEN);
    #pragma unroll
    for (int mt = 0; mt < 4; mt++) {
      #pragma unroll
      for (int r = 0; r < 4; r++) {
        int co = mt * 16 + q * 4 + r;
        float cb = conv_b[layer * 64 + co];
        ushort v = tok ? f2b(lrelu(a4[mt][r] + cb, 0.2f)) : (ushort)0;
        Ys[(jy * 8 + ((co >> 3) ^ (jy & 7))) * 8 + (co & 7)] = v;
      }
    }
  }

  // ---- phase 3: LVC MFMA (As staged per-ks over dead HWs) ----
  const ushort* kp = kern4 + ((size_t)layer * 512 + col) * LROWS;
  int n0w = w * 32;
  f4 acc[8][2] = {};
  for (int ks = 0; ks < 3; ks++) {
    __syncthreads();                   // Ys+HWs-reads done (1st) / As reuse (later)
    for (int g = tid; g < 1024; g += 512) {
      us8 v = *(const us8*)(kp + ks * 8192 + g * 8);
      int co = g >> 3, ch = g & 7;
      *(us8*)(&Asp[((g & ~7) | (ch ^ (co & 7))) * 8]) = v;
    }
    __syncthreads();
    #pragma unroll
    for (int kst = 0; kst < 2; kst++) {
      bh8 bfr[2];
      #pragma unroll
      for (int nt = 0; nt < 2; nt++) {
        int j = n0w + nt * 16 + ln + ks;
        int row = j + 7;               // Ys row base is t0-8; y[t0-1+j] = Ys[j+7]
        bfr[nt] = *(const bh8*)(&Ys[(row * 8 + ((kst * 4 + q) ^ (row & 7))) * 8]);
      }
      #pragma unroll
      for (int mt = 0; mt < 8; mt++) {
        int co = mt * 16 + ln;
        bh8 a = *(const bh8*)(&Asp[(co * 8 + ((kst * 4 + q) ^ (co & 7))) * 8]);
        #pragma unroll
        for (int nt = 0; nt < 2; nt++) acc[mt][nt] = mfma16(a, bfr[nt], acc[mt][nt]);
      }
    }
  }

  // ---- phase 4: gate epilogue, h_out = h_in + sig*tanh ----
  float* hbo = h_out + (size_t)b * 64 * OLEN;
  const float* bp = bias_all + (size_t)(b * 512 + layer * 128) * 128 + l;
  #pragma unroll
  for (int mt = 0; mt < 4; mt++) {
    #pragma unroll
    for (int nt = 0; nt < 2; nt++) {
      int t = t0 + n0w + nt * 16 + ln;
      #pragma unroll
      for (int r = 0; r < 4; r++) {
        int co = mt * 16 + q * 4 + r;
        float lo = acc[mt][nt][r] + bp[(size_t)co * 128];
        float hi = acc[mt + 4][nt][r] + bp[(size_t)(co + 64) * 128];
        float sg = __builtin_amdgcn_rcpf(1.f + __expf(-lo));
        float e2 = __expf(-2.f * fabsf(hi));
        float th = __builtin_amdgcn_rcpf(1.f + e2) * (1.f - e2);
        th = copysignf(th, hi);
        hbo[(size_t)co * OLEN + t] = hbin[(size_t)co * OLEN + t] + sg * th;
      }
    }
  }
}

extern "C" void kernel_launch(void* const* d_in, const int* in_sizes, int n_in,
                              void* d_out, int out_size, void* d_ws, size_t ws_size,
                              hipStream_t stream) {
  const float* x      = (const float*)d_in[0];
  const float* c      = (const float*)d_in[1];
  const float* up_w   = (const float*)d_in[2];
  const float* up_b   = (const float*)d_in[3];
  const float* kin_w  = (const float*)d_in[4];
  const float* kin_b  = (const float*)d_in[5];
  const float* kres_w = (const float*)d_in[6];
  const float* kres_b = (const float*)d_in[7];
  const float* kk_w   = (const float*)d_in[8];
  const float* kk_b   = (const float*)d_in[9];
  const float* kb_w   = (const float*)d_in[10];
  const float* kb_b   = (const float*)d_in[11];
  const float* conv_w = (const float*)d_in[12];
  const float* conv_b = (const float*)d_in[13];
  float* h = (float*)d_out;

  float* ws = (float*)d_ws;
  float* hsum     = ws; ws += 4 * 64 * 128;
  float* bias_all = ws; ws += 4 * 512 * 128;
  float* h2       = ws; ws += (size_t)4 * 64 * OLEN;
  ushort* kern4   = (ushort*)ws; ws += (size_t)4 * 512 * LROWS / 2;
  ushort* Bim     = (ushort*)ws; ws += 4 * 128 * 192 / 2;
  ushort* xT      = (ushort*)ws; ws += 4 * 4098 * 64 / 2 + 64;
  ushort* A3      = (ushort*)ws; ws += 512 * 192 / 2;
  ushort* wct_b   = (ushort*)ws; ws += 4 * 3 * 64 * 64 / 2;
  ushort* Ah      = (ushort*)ws; ws += 64 * 480 / 2;
  ushort* Ar      = (ushort*)ws; ws += 6 * 64 * 192 / 2;

  mega_prep<<<936, 256, 0, stream>>>(kin_w, kres_w, conv_w, up_w, x, Ah, Ar, wct_b, A3, xT);
  kp_fused<<<dim3(16, 4), 512, 0, stream>>>(c, Ah, kin_b, Ar, kres_b, hsum, Bim);
  mid_fused<<<dim3(1424, 4), 256, 0, stream>>>(kk_w, kk_b, Bim, kern4,
                                               kb_w, kb_b, bias_all,
                                               xT, A3, up_b, h);

  // h ping-pong: d_out -> h2 -> d_out -> h2 -> d_out
  float* hA = h;
  float* hB = h2;
  for (int layer = 0; layer < NLAYERS; layer++) {
    switch (layer) {
      case 0: conv_lvc_gate<1><<<dim3(128, 4), 512, 0, stream>>>(hA, wct_b, conv_b, kern4, bias_all, layer, hB); break;
      case 1: conv_lvc_gate<3><<<dim3(128, 4), 512, 0, stream>>>(hA, wct_b, conv_b, kern4, bias_all, layer, hB); break;
      case 2: conv_lvc_gate<9><<<dim3(128, 4), 512, 0, stream>>>(hA, wct_b, conv_b, kern4, bias_all, layer, hB); break;
      case 3: conv_lvc_gate<27><<<dim3(128, 4), 512, 0, stream>>>(hA, wct_b, conv_b, kern4, bias_all, layer, hB); break;
    }
    float* tmp = hA; hA = hB; hB = tmp;
  }
}